// Round 6
// baseline (261.177 us; speedup 1.0000x reference)
//
#include <hip/hip_runtime.h>
#include <math.h>

#define BB    16
#define NN    64
#define EE    512
#define CIMG  512
#define H1D   256
#define H2D   128
#define H3D   64
#define UD    8
#define RD    8
#define BBCD  9
#define EH1D  64
#define EH2D  64
#define EPSF  1e-5f

typedef float nfloat4 __attribute__((ext_vector_type(4)));  // native vec for nontemporal builtins

// ---------------------------------------------------------------------------
// Launch A (fused, all paths independent):
//   blocks [0,16)        prep: see/cnt via per-dst ordered scan
//   blocks [16,272)      node MLP (K-split across waves, LDS reduction)
//   blocks [272,1296)    edge MLP per (b,i); P/Q computed INLINE from
//                        attr+we1 (no prep dependency, no P/Q round-trip)
//   blocks [1296,2320)   full-slab NT zero-fill of out_edge (gather
//                        overwrites the corner in launch B)
// Duration ~= the 134 MB zero write; everything else hides under it.
// ---------------------------------------------------------------------------
__global__ __launch_bounds__(256) void fusedA_kernel(
    const int* __restrict__ edge_index,
    const float* __restrict__ bboxes,
    const float* __restrict__ dirs,
    const float* __restrict__ prios,
    const float* __restrict__ we1, const float* __restrict__ be1,
    int* __restrict__ see, int* __restrict__ cnt,
    const float* __restrict__ roi,
    const float* __restrict__ w1, const float* __restrict__ b1,
    const float* __restrict__ g1, const float* __restrict__ bt1,
    const float* __restrict__ m1, const float* __restrict__ v1,
    const float* __restrict__ w2, const float* __restrict__ b2,
    const float* __restrict__ g2, const float* __restrict__ bt2,
    const float* __restrict__ m2, const float* __restrict__ v2,
    const float* __restrict__ w3, const float* __restrict__ b3,
    const float* __restrict__ wn, const float* __restrict__ bnc,
    float* __restrict__ node_c,
    const float* __restrict__ we2, const float* __restrict__ be2,
    const float* __restrict__ wei, const float* __restrict__ bei,
    float* __restrict__ rel,
    float* __restrict__ out_edge)
{
    __shared__ union {
        struct {                       // prep path
            int src[EE];
            int dst[EE];
            int see[NN * NN];
        } p;
        struct {                       // node MLP path
            float part[4096];
            float h1[4][H1D];
            float h2[4][H2D];
            float h3[4][H3D];
        } n;
        struct {                       // edge MLP path
            float e1[NN * 68];         // e1 then e2 (row stride 68)
            float qw[NN * EH1D];       // we2
            float wei[EH2D * RD];
            float attr[NN][BBCD];
            float we1[2 * BBCD * EH1D];
            float Pi[EH1D];            // P[i] + be1 folded in
            float be2[EH2D];
            float bei[RD];
        } e;
    } sm;

    const int t = threadIdx.x;

    // ======================== zero-fill path ===============================
    if (blockIdx.x >= BB + 256 + BB * NN) {
        const int id = blockIdx.x - (BB + 256 + BB * NN);
        nfloat4* dst = (nfloat4*)(out_edge + (size_t)id * NN * NN * RD);
        const nfloat4 z = {0.f, 0.f, 0.f, 0.f};
        #pragma unroll
        for (int it = 0; it < 16; ++it) {
            int task = it * 256 + t;
            __builtin_nontemporal_store(z, dst + task * 2);
            __builtin_nontemporal_store(z, dst + task * 2 + 1);
        }
        return;
    }

    // ======================== prep path ====================================
    if (blockIdx.x < BB) {
        const int b = blockIdx.x;
        const int* ei = edge_index + b * 2 * EE;
        for (int e = t; e < EE; e += 256) {
            sm.p.src[e] = ei[e];
            sm.p.dst[e] = ei[EE + e];
        }
        for (int x = t; x < NN * NN; x += 256)
            sm.p.see[x] = ((x & (NN - 1)) == 0) ? (x >> 6) : 0;
        __syncthreads();

        if (t < NN) {
            int pos = 0;
            #pragma unroll 8
            for (int e = 0; e < EE; ++e) {
                if (sm.p.dst[e] == t) {
                    ++pos;
                    if (pos < NN) sm.p.see[t * NN + pos] = sm.p.src[e];
                }
            }
            int c = pos + 1;
            cnt[b * NN + t] = (c < NN) ? c : NN;
        }
        __syncthreads();

        int4* dst4 = (int4*)(see + b * NN * NN);
        const int4* src4 = (const int4*)sm.p.see;
        for (int x = t; x < (NN * NN) / 4; x += 256) dst4[x] = src4[x];
        return;
    }

    // ======================== edge MLP path ================================
    if (blockIdx.x >= BB + 256) {
        const int id = blockIdx.x - (BB + 256);
        const int b = id >> 6;
        const int i = id & 63;

        // stage attr, we1, we2, wei, biases
        if (t < NN) {
            const float* bbp = bboxes + (b * NN + t) * 4;
            const float* ddp = dirs + (b * NN + t) * 4;
            sm.e.attr[t][0] = bbp[0] * (1.0f / 1024.0f);
            sm.e.attr[t][1] = bbp[1] * (1.0f / 1024.0f);
            sm.e.attr[t][2] = bbp[2] * (1.0f / 1024.0f);
            sm.e.attr[t][3] = bbp[3] * (1.0f / 1024.0f);
            sm.e.attr[t][4] = ddp[0];
            sm.e.attr[t][5] = ddp[1];
            sm.e.attr[t][6] = ddp[2];
            sm.e.attr[t][7] = ddp[3];
            sm.e.attr[t][8] = prios[b * NN + t];
        }
        for (int x = t; x < 2 * BBCD * EH1D; x += 256) sm.e.we1[x] = we1[x];
        {
            const float4* w4 = (const float4*)we2;
            float4* qw4 = (float4*)sm.e.qw;
            #pragma unroll
            for (int x = 0; x < 4; ++x) qw4[x * 256 + t] = w4[x * 256 + t];
        }
        if (t < 128) ((float4*)sm.e.wei)[t] = ((const float4*)wei)[t];
        if (t < EH2D) sm.e.be2[t] = be2[t];
        if (t < RD) sm.e.bei[t] = bei[t];
        __syncthreads();

        // Pi[o] = attr[i] @ we1[:9, o] + be1[o]
        if (t < EH1D) {
            float p = be1[t];
            #pragma unroll
            for (int c = 0; c < BBCD; ++c)
                p = fmaf(sm.e.attr[i][c], sm.e.we1[c * EH1D + t], p);
            sm.e.Pi[t] = p;
        }
        __syncthreads();

        // e1[j][o] = relu(Pi[o] + attr[j] @ we1[9:, o]); j wave-uniform
        {
            const int o = t & 63;
            const int jw = t >> 6;       // wave index, uniform
            #pragma unroll
            for (int jg = 0; jg < 16; ++jg) {
                const int j = jg * 4 + jw;
                float a = sm.e.Pi[o];
                #pragma unroll
                for (int c = 0; c < BBCD; ++c)
                    a = fmaf(sm.e.attr[j][c], sm.e.we1[(BBCD + c) * EH1D + o], a);
                sm.e.e1[j * 68 + o] = fmaxf(0.f, a);
            }
        }
        __syncthreads();

        // e2[j][o2] = relu(e1 @ we2 + be2) via 4x4 register blocking
        const int tx = t & 15, ty = t >> 4;
        const int o0 = tx * 4, j0 = ty * 4;
        float acc[4][4];
        #pragma unroll
        for (int r = 0; r < 4; ++r)
            #pragma unroll
            for (int o = 0; o < 4; ++o) acc[r][o] = 0.f;

        #pragma unroll 4
        for (int cg = 0; cg < 16; ++cg) {
            float ev[4][4];
            #pragma unroll
            for (int r = 0; r < 4; ++r) {
                float4 v = *(const float4*)(sm.e.e1 + (j0 + r) * 68 + cg * 4);
                ev[r][0] = v.x; ev[r][1] = v.y; ev[r][2] = v.z; ev[r][3] = v.w;
            }
            #pragma unroll
            for (int q = 0; q < 4; ++q) {
                float4 wv = *(const float4*)(sm.e.qw + (cg * 4 + q) * EH1D + o0);
                #pragma unroll
                for (int r = 0; r < 4; ++r) {
                    acc[r][0] = fmaf(ev[r][q], wv.x, acc[r][0]);
                    acc[r][1] = fmaf(ev[r][q], wv.y, acc[r][1]);
                    acc[r][2] = fmaf(ev[r][q], wv.z, acc[r][2]);
                    acc[r][3] = fmaf(ev[r][q], wv.w, acc[r][3]);
                }
            }
        }

        {
            float4 bv = *(const float4*)(sm.e.be2 + o0);
            #pragma unroll
            for (int r = 0; r < 4; ++r) {
                float4 v;
                v.x = fmaxf(0.f, acc[r][0] + bv.x);
                v.y = fmaxf(0.f, acc[r][1] + bv.y);
                v.z = fmaxf(0.f, acc[r][2] + bv.z);
                v.w = fmaxf(0.f, acc[r][3] + bv.w);
                *(float4*)(sm.e.e1 + (j0 + r) * 68 + o0) = v;
            }
        }
        __syncthreads();

        // layer 3 + sigmoid: thread (j = t>>2, r0 = (t&3)*2) -> 2 outputs
        {
            const int j = t >> 2;
            const int r0 = (t & 3) * 2;
            float a0 = sm.e.bei[r0], a1 = sm.e.bei[r0 + 1];
            const float* e2row = sm.e.e1 + j * 68;
            #pragma unroll
            for (int og = 0; og < 16; ++og) {
                float4 e2v = *(const float4*)(e2row + og * 4);
                float2 w0 = *(const float2*)(sm.e.wei + (og * 4 + 0) * RD + r0);
                float2 w1 = *(const float2*)(sm.e.wei + (og * 4 + 1) * RD + r0);
                float2 w2 = *(const float2*)(sm.e.wei + (og * 4 + 2) * RD + r0);
                float2 w3 = *(const float2*)(sm.e.wei + (og * 4 + 3) * RD + r0);
                a0 = fmaf(e2v.x, w0.x, a0); a1 = fmaf(e2v.x, w0.y, a1);
                a0 = fmaf(e2v.y, w1.x, a0); a1 = fmaf(e2v.y, w1.y, a1);
                a0 = fmaf(e2v.z, w2.x, a0); a1 = fmaf(e2v.z, w2.y, a1);
                a0 = fmaf(e2v.w, w3.x, a0); a1 = fmaf(e2v.w, w3.y, a1);
            }
            float2 o;
            o.x = 1.f / (1.f + expf(-a0));
            o.y = 1.f / (1.f + expf(-a1));
            *(float2*)(rel + ((size_t)id * NN + j) * RD + r0) = o;
        }
        return;
    }

    // ======================== node MLP path ================================
    const int row0 = (blockIdx.x - BB) * 4;
    float* part = sm.n.part;

    // layer 1: 512 -> 256. og = t&63 (4 cols), kg = t>>6 (K/4 slice)
    {
        const int og = t & 63, kg = t >> 6;
        const float4* w1v = (const float4*)w1;
        const float4* roiv = (const float4*)(roi + (size_t)row0 * CIMG);
        float acc[4][4];
        #pragma unroll
        for (int r = 0; r < 4; ++r)
            #pragma unroll
            for (int c = 0; c < 4; ++c) acc[r][c] = 0.f;

        for (int cq = 0; cq < 32; ++cq) {
            const int c4 = kg * 32 + cq;
            float x[4][4], w[4][4];
            #pragma unroll
            for (int r = 0; r < 4; ++r) {
                float4 v = roiv[r * 128 + c4];
                x[r][0] = v.x; x[r][1] = v.y; x[r][2] = v.z; x[r][3] = v.w;
            }
            #pragma unroll
            for (int q = 0; q < 4; ++q) {
                float4 v = w1v[(size_t)(c4 * 4 + q) * 64 + og];
                w[q][0] = v.x; w[q][1] = v.y; w[q][2] = v.z; w[q][3] = v.w;
            }
            #pragma unroll
            for (int r = 0; r < 4; ++r)
                #pragma unroll
                for (int q = 0; q < 4; ++q)
                    #pragma unroll
                    for (int c = 0; c < 4; ++c)
                        acc[r][c] = fmaf(x[r][q], w[q][c], acc[r][c]);
        }
        #pragma unroll
        for (int r = 0; r < 4; ++r) {
            float4 v = {acc[r][0], acc[r][1], acc[r][2], acc[r][3]};
            *(float4*)(part + (kg * 4 + r) * 256 + og * 4) = v;
        }
    }
    __syncthreads();
    {
        const int o = t;
        const float bias = b1[o];
        const float scale = rsqrtf(v1[o] + EPSF) * g1[o];
        const float beta = bt1[o];
        const float mu = m1[o];
        #pragma unroll
        for (int r = 0; r < 4; ++r) {
            float s = part[(0 * 4 + r) * 256 + o] + part[(1 * 4 + r) * 256 + o]
                    + part[(2 * 4 + r) * 256 + o] + part[(3 * 4 + r) * 256 + o];
            sm.n.h1[r][o] = fmaxf(0.f, (s + bias - mu) * scale + beta);
        }
    }
    __syncthreads();

    // layer 2: 256 -> 128. og = t&31, kg = t>>5
    {
        const int og = t & 31, kg = t >> 5;
        const float4* w2v = (const float4*)w2;
        float acc[4][4];
        #pragma unroll
        for (int r = 0; r < 4; ++r)
            #pragma unroll
            for (int c = 0; c < 4; ++c) acc[r][c] = 0.f;

        #pragma unroll
        for (int cq = 0; cq < 8; ++cq) {
            const int c4 = kg * 8 + cq;
            float x[4][4], w[4][4];
            #pragma unroll
            for (int r = 0; r < 4; ++r) {
                float4 v = *(const float4*)&sm.n.h1[r][c4 * 4];
                x[r][0] = v.x; x[r][1] = v.y; x[r][2] = v.z; x[r][3] = v.w;
            }
            #pragma unroll
            for (int q = 0; q < 4; ++q) {
                float4 v = w2v[(size_t)(c4 * 4 + q) * 32 + og];
                w[q][0] = v.x; w[q][1] = v.y; w[q][2] = v.z; w[q][3] = v.w;
            }
            #pragma unroll
            for (int r = 0; r < 4; ++r)
                #pragma unroll
                for (int q = 0; q < 4; ++q)
                    #pragma unroll
                    for (int c = 0; c < 4; ++c)
                        acc[r][c] = fmaf(x[r][q], w[q][c], acc[r][c]);
        }
        #pragma unroll
        for (int r = 0; r < 4; ++r) {
            float4 v = {acc[r][0], acc[r][1], acc[r][2], acc[r][3]};
            *(float4*)(part + (kg * 4 + r) * 128 + og * 4) = v;
        }
    }
    __syncthreads();
    {
        const int o = t & 127;
        const int rp = t >> 7;
        const float bias = b2[o];
        const float scale = rsqrtf(v2[o] + EPSF) * g2[o];
        const float beta = bt2[o];
        const float mu = m2[o];
        #pragma unroll
        for (int rr = 0; rr < 2; ++rr) {
            const int r = rp + rr * 2;
            float s = 0.f;
            #pragma unroll
            for (int kg = 0; kg < 8; ++kg) s += part[(kg * 4 + r) * 128 + o];
            sm.n.h2[r][o] = fmaxf(0.f, (s + bias - mu) * scale + beta);
        }
    }
    __syncthreads();

    // layer 3: 128 -> 64. og = t&15, kg = t>>4
    {
        const int og = t & 15, kg = t >> 4;
        const float4* w3v = (const float4*)w3;
        float acc[4][4];
        #pragma unroll
        for (int r = 0; r < 4; ++r)
            #pragma unroll
            for (int c = 0; c < 4; ++c) acc[r][c] = 0.f;

        #pragma unroll
        for (int cq = 0; cq < 2; ++cq) {
            const int c4 = kg * 2 + cq;
            float x[4][4], w[4][4];
            #pragma unroll
            for (int r = 0; r < 4; ++r) {
                float4 v = *(const float4*)&sm.n.h2[r][c4 * 4];
                x[r][0] = v.x; x[r][1] = v.y; x[r][2] = v.z; x[r][3] = v.w;
            }
            #pragma unroll
            for (int q = 0; q < 4; ++q) {
                float4 v = w3v[(size_t)(c4 * 4 + q) * 16 + og];
                w[q][0] = v.x; w[q][1] = v.y; w[q][2] = v.z; w[q][3] = v.w;
            }
            #pragma unroll
            for (int r = 0; r < 4; ++r)
                #pragma unroll
                for (int q = 0; q < 4; ++q)
                    #pragma unroll
                    for (int c = 0; c < 4; ++c)
                        acc[r][c] = fmaf(x[r][q], w[q][c], acc[r][c]);
        }
        #pragma unroll
        for (int r = 0; r < 4; ++r) {
            float4 v = {acc[r][0], acc[r][1], acc[r][2], acc[r][3]};
            *(float4*)(part + (kg * 4 + r) * 64 + og * 4) = v;
        }
    }
    __syncthreads();
    {
        const int o = t & 63;
        const int r = t >> 6;
        float s = b3[o];
        #pragma unroll
        for (int kg = 0; kg < 16; ++kg) s += part[(kg * 4 + r) * 64 + o];
        sm.n.h3[r][o] = fmaxf(0.f, s);
    }
    __syncthreads();

    // layer 4 + sigmoid
    if (t < 32) {
        const int o = t & 7, r = t >> 3;
        float a = bnc[o];
        #pragma unroll 8
        for (int c = 0; c < H3D; ++c) a = fmaf(sm.n.h3[r][c], wn[c * UD + o], a);
        node_c[(size_t)(row0 + r) * UD + o] = 1.f / (1.f + expf(-a));
    }
}

// ---------------------------------------------------------------------------
// Launch B: sparse corner gather (j,k < cnt) + node concepts row. Zeros were
// written by launch A's full-slab fill. Grid: 1024 x 256.
// ---------------------------------------------------------------------------
__global__ __launch_bounds__(256) void gather_kernel(
    const int* __restrict__ see, const int* __restrict__ cnt,
    const float* __restrict__ node_c, const float* __restrict__ rel,
    float* __restrict__ out_node, float* __restrict__ out_edge)
{
    __shared__ int s_s[NN];

    const int t = threadIdx.x;
    const int bi = blockIdx.x;        // b*NN + i
    const int b = bi >> 6;
    const int c = cnt[bi];

    if (t < NN) s_s[t] = see[bi * NN + t];
    __syncthreads();

    if (t < NN) {
        const float m = (t < c) ? 1.f : 0.f;
        const float4* src = (const float4*)(node_c + (size_t)(b * NN + s_s[t]) * UD);
        float4 v0 = src[0], v1 = src[1];
        v0.x *= m; v0.y *= m; v0.z *= m; v0.w *= m;
        v1.x *= m; v1.y *= m; v1.z *= m; v1.w *= m;
        float4* dst = (float4*)(out_node + ((size_t)bi * NN + t) * UD);
        dst[0] = v0;
        dst[1] = v1;
    }

    const float* relb = rel + (size_t)b * NN * NN * RD;
    float* outb = out_edge + (size_t)bi * NN * NN * RD;

    const int total = c * c;
    for (int task = t; task < total; task += 256) {
        int j = task / c;
        int k = task - j * c;
        const float4* src =
            (const float4*)(relb + (size_t)(s_s[j] * NN + s_s[k]) * RD);
        float4 v0 = src[0], v1 = src[1];
        float4* dst = (float4*)(outb + ((size_t)j * NN + k) * RD);
        dst[0] = v0;
        dst[1] = v1;
    }
}

// ---------------------------------------------------------------------------
extern "C" void kernel_launch(void* const* d_in, const int* in_sizes, int n_in,
                              void* d_out, int out_size, void* d_ws, size_t ws_size,
                              hipStream_t stream)
{
    const float* roi  = (const float*)d_in[0];
    const float* bbox = (const float*)d_in[1];
    const float* dirs = (const float*)d_in[2];
    const float* prio = (const float*)d_in[3];
    const float* w1   = (const float*)d_in[4];
    const float* b1   = (const float*)d_in[5];
    const float* g1   = (const float*)d_in[6];
    const float* bt1  = (const float*)d_in[7];
    const float* m1   = (const float*)d_in[8];
    const float* v1   = (const float*)d_in[9];
    const float* w2   = (const float*)d_in[10];
    const float* b2   = (const float*)d_in[11];
    const float* g2   = (const float*)d_in[12];
    const float* bt2  = (const float*)d_in[13];
    const float* m2   = (const float*)d_in[14];
    const float* v2   = (const float*)d_in[15];
    const float* w3   = (const float*)d_in[16];
    const float* b3   = (const float*)d_in[17];
    const float* wn   = (const float*)d_in[18];
    const float* bnc  = (const float*)d_in[19];
    const float* we1  = (const float*)d_in[20];
    const float* be1  = (const float*)d_in[21];
    const float* we2  = (const float*)d_in[22];
    const float* be2  = (const float*)d_in[23];
    const float* wei  = (const float*)d_in[24];
    const float* bei  = (const float*)d_in[25];
    const int* edge_index = (const int*)d_in[26];

    char* ws = (char*)d_ws;
    int*   see    = (int*)ws;   ws += (size_t)BB * NN * NN * 4;
    int*   cnt    = (int*)ws;   ws += (size_t)BB * NN * 4;
    float* node_c = (float*)ws; ws += (size_t)BB * NN * UD * 4;
    float* rel    = (float*)ws; ws += (size_t)BB * NN * NN * RD * 4;

    float* out_node = (float*)d_out;
    float* out_edge = (float*)d_out + (size_t)BB * NN * NN * UD;

    hipLaunchKernelGGL(fusedA_kernel,
                       dim3(BB + 256 + BB * NN + BB * NN), dim3(256), 0, stream,
                       edge_index, bbox, dirs, prio, we1, be1,
                       see, cnt,
                       roi, w1, b1, g1, bt1, m1, v1,
                       w2, b2, g2, bt2, m2, v2,
                       w3, b3, wn, bnc, node_c,
                       we2, be2, wei, bei, rel, out_edge);
    hipLaunchKernelGGL(gather_kernel, dim3(BB * NN), dim3(256), 0, stream,
                       see, cnt, node_c, rel, out_node, out_edge);
}

// Round 7
// 250.886 us; speedup vs baseline: 1.0410x; 1.0410x over previous
//
#include <hip/hip_runtime.h>
#include <math.h>

#define BB    16
#define NN    64
#define EE    512
#define CIMG  512
#define H1D   256
#define H2D   128
#define H3D   64
#define UD    8
#define RD    8
#define BBCD  9
#define EH1D  64
#define EH2D  64
#define EPSF  1e-5f

typedef float nfloat4 __attribute__((ext_vector_type(4)));  // native vec for nontemporal builtins

// ---------------------------------------------------------------------------
// Kernel 1 (fused): blocks [0,16) prep | [16,272) node MLP | [272,1296)
// full-slab zero-fill of out_edge (gather overwrites the corner in launch 3).
// LDS union kept at 23 KB (node path) so the fill path runs ~6 blocks/CU —
// R6 showed that a 43 KB union (edge path merged in) throttles the
// write-bound fill to 3 blocks/CU and regresses ~11 us.
// Node MLP: K-split across waves — unique per-thread weight slices (no
// cross-wave L1 redundancy), wave-uniform activation loads, LDS reduction.
// ---------------------------------------------------------------------------
__global__ __launch_bounds__(256) void fused1_kernel(
    const int* __restrict__ edge_index,
    const float* __restrict__ bboxes,
    const float* __restrict__ dirs,
    const float* __restrict__ prios,
    const float* __restrict__ we1,
    const float* __restrict__ be1,
    int* __restrict__ see, int* __restrict__ cnt,
    float* __restrict__ P, float* __restrict__ Q,
    const float* __restrict__ roi,
    const float* __restrict__ w1, const float* __restrict__ b1,
    const float* __restrict__ g1, const float* __restrict__ bt1,
    const float* __restrict__ m1, const float* __restrict__ v1,
    const float* __restrict__ w2, const float* __restrict__ b2,
    const float* __restrict__ g2, const float* __restrict__ bt2,
    const float* __restrict__ m2, const float* __restrict__ v2,
    const float* __restrict__ w3, const float* __restrict__ b3,
    const float* __restrict__ wn, const float* __restrict__ bnc,
    float* __restrict__ node_c,
    float* __restrict__ out_edge)
{
    __shared__ union {
        struct {
            int src[EE];
            int dst[EE];
            int see[NN * NN];
            float attr[NN][BBCD];
        } p;
        struct {
            float part[4096];      // K-split partial sums (reused per layer)
            float h1[4][H1D];
            float h2[4][H2D];
            float h3[4][H3D];
        } n;
    } sm;

    const int t = threadIdx.x;

    if (blockIdx.x >= BB + 256) {
        // ---------------- zero-fill path: full slab, NT stores -------------
        const int id = blockIdx.x - (BB + 256);       // (b,i) slab
        nfloat4* dst = (nfloat4*)(out_edge + (size_t)id * NN * NN * RD);
        const nfloat4 z = {0.f, 0.f, 0.f, 0.f};
        #pragma unroll
        for (int it = 0; it < 16; ++it) {
            int task = it * 256 + t;
            __builtin_nontemporal_store(z, dst + task * 2);
            __builtin_nontemporal_store(z, dst + task * 2 + 1);
        }
        return;
    }

    if (blockIdx.x < BB) {
        // ------------------------- prep path -------------------------------
        const int b = blockIdx.x;
        const int* ei = edge_index + b * 2 * EE;
        for (int e = t; e < EE; e += 256) {
            sm.p.src[e] = ei[e];
            sm.p.dst[e] = ei[EE + e];
        }
        for (int x = t; x < NN * NN; x += 256)
            sm.p.see[x] = ((x & (NN - 1)) == 0) ? (x >> 6) : 0;
        if (t < NN) {
            const float* bbp = bboxes + (b * NN + t) * 4;
            const float* ddp = dirs + (b * NN + t) * 4;
            sm.p.attr[t][0] = bbp[0] * (1.0f / 1024.0f);
            sm.p.attr[t][1] = bbp[1] * (1.0f / 1024.0f);
            sm.p.attr[t][2] = bbp[2] * (1.0f / 1024.0f);
            sm.p.attr[t][3] = bbp[3] * (1.0f / 1024.0f);
            sm.p.attr[t][4] = ddp[0];
            sm.p.attr[t][5] = ddp[1];
            sm.p.attr[t][6] = ddp[2];
            sm.p.attr[t][7] = ddp[3];
            sm.p.attr[t][8] = prios[b * NN + t];
        }
        __syncthreads();

        if (t < NN) {
            int pos = 0;
            #pragma unroll 8
            for (int e = 0; e < EE; ++e) {
                if (sm.p.dst[e] == t) {
                    ++pos;
                    if (pos < NN) sm.p.see[t * NN + pos] = sm.p.src[e];
                }
            }
            int c = pos + 1;
            cnt[b * NN + t] = (c < NN) ? c : NN;
        }
        __syncthreads();

        {
            int4* dst4 = (int4*)(see + b * NN * NN);
            const int4* src4 = (const int4*)sm.p.see;
            for (int x = t; x < (NN * NN) / 4; x += 256) dst4[x] = src4[x];
        }

        for (int x = t; x < NN * EH1D; x += 256) {
            int n = x >> 6, o = x & 63;
            float p = 0.f;
            float q = be1[o];
            #pragma unroll
            for (int c = 0; c < BBCD; ++c) {
                float a = sm.p.attr[n][c];
                p = fmaf(a, we1[c * EH1D + o], p);
                q = fmaf(a, we1[(BBCD + c) * EH1D + o], q);
            }
            P[(b * NN + n) * EH1D + o] = p;
            Q[(b * NN + n) * EH1D + o] = q;
        }
        return;
    }

    // --------------------------- node MLP path -----------------------------
    const int row0 = (blockIdx.x - BB) * 4;
    float* part = sm.n.part;

    // ---- layer 1: 512 -> 256. og = t&63 (cols og*4..+4), kg = t>>6 (K/4 slice)
    {
        const int og = t & 63, kg = t >> 6;
        const float4* w1v = (const float4*)w1;                 // [c][64] quads
        const float4* roiv = (const float4*)(roi + (size_t)row0 * CIMG); // [r][128] quads
        float acc[4][4];
        #pragma unroll
        for (int r = 0; r < 4; ++r)
            #pragma unroll
            for (int c = 0; c < 4; ++c) acc[r][c] = 0.f;

        for (int cq = 0; cq < 32; ++cq) {
            const int c4 = kg * 32 + cq;    // wave-uniform
            float x[4][4], w[4][4];
            #pragma unroll
            for (int r = 0; r < 4; ++r) {
                float4 v = roiv[r * 128 + c4];                  // wave-uniform addr
                x[r][0] = v.x; x[r][1] = v.y; x[r][2] = v.z; x[r][3] = v.w;
            }
            #pragma unroll
            for (int q = 0; q < 4; ++q) {
                float4 v = w1v[(size_t)(c4 * 4 + q) * 64 + og]; // unique per thread
                w[q][0] = v.x; w[q][1] = v.y; w[q][2] = v.z; w[q][3] = v.w;
            }
            #pragma unroll
            for (int r = 0; r < 4; ++r)
                #pragma unroll
                for (int q = 0; q < 4; ++q)
                    #pragma unroll
                    for (int c = 0; c < 4; ++c)
                        acc[r][c] = fmaf(x[r][q], w[q][c], acc[r][c]);
        }
        // partials: part[kg][r][o], o = og*4+c  (b128 store, 2-way = free)
        #pragma unroll
        for (int r = 0; r < 4; ++r) {
            float4 v = {acc[r][0], acc[r][1], acc[r][2], acc[r][3]};
            *(float4*)(part + (kg * 4 + r) * 256 + og * 4) = v;
        }
    }
    __syncthreads();
    {
        // reduce over kg: thread t = output o  (b32 reads, conflict-free)
        const int o = t;
        const float bias = b1[o];
        const float scale = rsqrtf(v1[o] + EPSF) * g1[o];
        const float beta = bt1[o];
        const float mu = m1[o];
        #pragma unroll
        for (int r = 0; r < 4; ++r) {
            float s = part[(0 * 4 + r) * 256 + o] + part[(1 * 4 + r) * 256 + o]
                    + part[(2 * 4 + r) * 256 + o] + part[(3 * 4 + r) * 256 + o];
            sm.n.h1[r][o] = fmaxf(0.f, (s + bias - mu) * scale + beta);
        }
    }
    __syncthreads();

    // ---- layer 2: 256 -> 128. og = t&31, kg = t>>5 (K/8 slice)
    {
        const int og = t & 31, kg = t >> 5;
        const float4* w2v = (const float4*)w2;                 // [c][32] quads
        float acc[4][4];
        #pragma unroll
        for (int r = 0; r < 4; ++r)
            #pragma unroll
            for (int c = 0; c < 4; ++c) acc[r][c] = 0.f;

        #pragma unroll
        for (int cq = 0; cq < 8; ++cq) {
            const int c4 = kg * 8 + cq;
            float x[4][4], w[4][4];
            #pragma unroll
            for (int r = 0; r < 4; ++r) {
                float4 v = *(const float4*)&sm.n.h1[r][c4 * 4]; // 2-addr broadcast
                x[r][0] = v.x; x[r][1] = v.y; x[r][2] = v.z; x[r][3] = v.w;
            }
            #pragma unroll
            for (int q = 0; q < 4; ++q) {
                float4 v = w2v[(size_t)(c4 * 4 + q) * 32 + og];
                w[q][0] = v.x; w[q][1] = v.y; w[q][2] = v.z; w[q][3] = v.w;
            }
            #pragma unroll
            for (int r = 0; r < 4; ++r)
                #pragma unroll
                for (int q = 0; q < 4; ++q)
                    #pragma unroll
                    for (int c = 0; c < 4; ++c)
                        acc[r][c] = fmaf(x[r][q], w[q][c], acc[r][c]);
        }
        #pragma unroll
        for (int r = 0; r < 4; ++r) {
            float4 v = {acc[r][0], acc[r][1], acc[r][2], acc[r][3]};
            *(float4*)(part + (kg * 4 + r) * 128 + og * 4) = v;
        }
    }
    __syncthreads();
    {
        // reduce: 512 tasks = 128 outs x 4 rows; thread handles 2 rows
        const int o = t & 127;
        const int rp = t >> 7;          // 0,1 -> rows {rp, rp+2}
        const float bias = b2[o];
        const float scale = rsqrtf(v2[o] + EPSF) * g2[o];
        const float beta = bt2[o];
        const float mu = m2[o];
        #pragma unroll
        for (int rr = 0; rr < 2; ++rr) {
            const int r = rp + rr * 2;
            float s = 0.f;
            #pragma unroll
            for (int kg = 0; kg < 8; ++kg) s += part[(kg * 4 + r) * 128 + o];
            sm.n.h2[r][o] = fmaxf(0.f, (s + bias - mu) * scale + beta);
        }
    }
    __syncthreads();

    // ---- layer 3: 128 -> 64. og = t&15, kg = t>>4 (K/16 slice)
    {
        const int og = t & 15, kg = t >> 4;
        const float4* w3v = (const float4*)w3;                 // [c][16] quads
        float acc[4][4];
        #pragma unroll
        for (int r = 0; r < 4; ++r)
            #pragma unroll
            for (int c = 0; c < 4; ++c) acc[r][c] = 0.f;

        #pragma unroll
        for (int cq = 0; cq < 2; ++cq) {
            const int c4 = kg * 2 + cq;
            float x[4][4], w[4][4];
            #pragma unroll
            for (int r = 0; r < 4; ++r) {
                float4 v = *(const float4*)&sm.n.h2[r][c4 * 4];
                x[r][0] = v.x; x[r][1] = v.y; x[r][2] = v.z; x[r][3] = v.w;
            }
            #pragma unroll
            for (int q = 0; q < 4; ++q) {
                float4 v = w3v[(size_t)(c4 * 4 + q) * 16 + og];
                w[q][0] = v.x; w[q][1] = v.y; w[q][2] = v.z; w[q][3] = v.w;
            }
            #pragma unroll
            for (int r = 0; r < 4; ++r)
                #pragma unroll
                for (int q = 0; q < 4; ++q)
                    #pragma unroll
                    for (int c = 0; c < 4; ++c)
                        acc[r][c] = fmaf(x[r][q], w[q][c], acc[r][c]);
        }
        #pragma unroll
        for (int r = 0; r < 4; ++r) {
            float4 v = {acc[r][0], acc[r][1], acc[r][2], acc[r][3]};
            *(float4*)(part + (kg * 4 + r) * 64 + og * 4) = v;
        }
    }
    __syncthreads();
    {
        // reduce: 256 tasks = 64 outs x 4 rows
        const int o = t & 63;
        const int r = t >> 6;
        float s = b3[o];
        #pragma unroll
        for (int kg = 0; kg < 16; ++kg) s += part[(kg * 4 + r) * 64 + o];
        sm.n.h3[r][o] = fmaxf(0.f, s);
    }
    __syncthreads();

    // ---- layer 4 + sigmoid: 64 -> 8, threads t<32 (o<8, r<4)
    if (t < 32) {
        const int o = t & 7, r = t >> 3;
        float a = bnc[o];
        #pragma unroll 8
        for (int c = 0; c < H3D; ++c) a = fmaf(sm.n.h3[r][c], wn[c * UD + o], a);
        node_c[(size_t)(row0 + r) * UD + o] = 1.f / (1.f + expf(-a));
    }
}

// ---------------------------------------------------------------------------
// Kernel 2: edge MLP. Block = (b,i): 64 j-rows x 64 o2, 256 threads, 4x4
// register blocking, all operands staged in LDS. Grid: BB*NN = 1024 blocks.
// ---------------------------------------------------------------------------
__global__ __launch_bounds__(256) void edge_mlp_kernel(
    const float* __restrict__ P, const float* __restrict__ Q,
    const float* __restrict__ we2, const float* __restrict__ be2,
    const float* __restrict__ wei, const float* __restrict__ bei,
    float* __restrict__ rel)
{
    __shared__ float e1_s[NN * 68];
    __shared__ float qw_s[NN * EH1D];
    __shared__ float wei_s[EH2D * RD];
    __shared__ float Pi_s[EH1D];
    __shared__ float be2_s[EH2D];
    __shared__ float bei_s[RD];

    const int t = threadIdx.x;
    const int b = blockIdx.x >> 6;
    const int i = blockIdx.x & 63;

    {
        const float4* Qb4 = (const float4*)(Q + (size_t)b * NN * EH1D);
        float4* qw4 = (float4*)qw_s;
        #pragma unroll
        for (int x = 0; x < 4; ++x) qw4[x * 256 + t] = Qb4[x * 256 + t];
        if (t < EH1D) Pi_s[t] = P[(size_t)(b * NN + i) * EH1D + t];
        if (t < 128) ((float4*)wei_s)[t] = ((const float4*)wei)[t];
        if (t < EH2D) be2_s[t] = be2[t];
        if (t < RD) bei_s[t] = bei[t];
    }
    __syncthreads();

    // e1[j][c] = relu(Pi[c] + Q[j][c])
    {
        const int j = t & 63, cg = t >> 6;
        const float4* qrow = (const float4*)(qw_s + j * EH1D);
        const float4* prow = (const float4*)Pi_s;
        #pragma unroll
        for (int q = 0; q < 4; ++q) {
            int c4 = cg * 4 + q;
            float4 qv = qrow[c4];
            float4 pv = prow[c4];
            float4 ev;
            ev.x = fmaxf(0.f, qv.x + pv.x);
            ev.y = fmaxf(0.f, qv.y + pv.y);
            ev.z = fmaxf(0.f, qv.z + pv.z);
            ev.w = fmaxf(0.f, qv.w + pv.w);
            *(float4*)(e1_s + j * 68 + c4 * 4) = ev;
        }
    }
    __syncthreads();

    // stage we2 into qw_s (Q is dead)
    {
        const float4* w4 = (const float4*)we2;
        float4* qw4 = (float4*)qw_s;
        #pragma unroll
        for (int x = 0; x < 4; ++x) qw4[x * 256 + t] = w4[x * 256 + t];
    }
    __syncthreads();

    // e2[j][o2] = relu(sum_c e1[j][c] * we2[c][o2] + be2[o2]) via 4x4 blocking
    const int tx = t & 15, ty = t >> 4;
    const int o0 = tx * 4, j0 = ty * 4;
    float acc[4][4];
    #pragma unroll
    for (int r = 0; r < 4; ++r)
        #pragma unroll
        for (int o = 0; o < 4; ++o) acc[r][o] = 0.f;

    #pragma unroll 4
    for (int cg = 0; cg < 16; ++cg) {
        float ev[4][4];
        #pragma unroll
        for (int r = 0; r < 4; ++r) {
            float4 v = *(const float4*)(e1_s + (j0 + r) * 68 + cg * 4);
            ev[r][0] = v.x; ev[r][1] = v.y; ev[r][2] = v.z; ev[r][3] = v.w;
        }
        #pragma unroll
        for (int q = 0; q < 4; ++q) {
            float4 wv = *(const float4*)(qw_s + (cg * 4 + q) * EH1D + o0);
            #pragma unroll
            for (int r = 0; r < 4; ++r) {
                acc[r][0] = fmaf(ev[r][q], wv.x, acc[r][0]);
                acc[r][1] = fmaf(ev[r][q], wv.y, acc[r][1]);
                acc[r][2] = fmaf(ev[r][q], wv.z, acc[r][2]);
                acc[r][3] = fmaf(ev[r][q], wv.w, acc[r][3]);
            }
        }
    }

    {
        float4 bv = *(const float4*)(be2_s + o0);
        #pragma unroll
        for (int r = 0; r < 4; ++r) {
            float4 v;
            v.x = fmaxf(0.f, acc[r][0] + bv.x);
            v.y = fmaxf(0.f, acc[r][1] + bv.y);
            v.z = fmaxf(0.f, acc[r][2] + bv.z);
            v.w = fmaxf(0.f, acc[r][3] + bv.w);
            *(float4*)(e1_s + (j0 + r) * 68 + o0) = v;
        }
    }
    __syncthreads();

    // layer 3 + sigmoid: thread (j = t>>2, r0 = (t&3)*2) -> 2 outputs
    {
        const int j = t >> 2;
        const int r0 = (t & 3) * 2;
        float a0 = bei_s[r0], a1 = bei_s[r0 + 1];
        const float* e2row = e1_s + j * 68;
        #pragma unroll
        for (int og = 0; og < 16; ++og) {
            float4 e2v = *(const float4*)(e2row + og * 4);
            float2 w0 = *(const float2*)(wei_s + (og * 4 + 0) * RD + r0);
            float2 w1 = *(const float2*)(wei_s + (og * 4 + 1) * RD + r0);
            float2 w2 = *(const float2*)(wei_s + (og * 4 + 2) * RD + r0);
            float2 w3 = *(const float2*)(wei_s + (og * 4 + 3) * RD + r0);
            a0 = fmaf(e2v.x, w0.x, a0); a1 = fmaf(e2v.x, w0.y, a1);
            a0 = fmaf(e2v.y, w1.x, a0); a1 = fmaf(e2v.y, w1.y, a1);
            a0 = fmaf(e2v.z, w2.x, a0); a1 = fmaf(e2v.z, w2.y, a1);
            a0 = fmaf(e2v.w, w3.x, a0); a1 = fmaf(e2v.w, w3.y, a1);
        }
        float2 o;
        o.x = 1.f / (1.f + expf(-a0));
        o.y = 1.f / (1.f + expf(-a1));
        *(float2*)(rel + ((size_t)(b * NN + i) * NN + j) * RD + r0) = o;
    }
}

// ---------------------------------------------------------------------------
// Kernel 3: sparse corner gather (j,k < cnt) + node concepts row. The zeros
// were already written by fused1's full-slab fill. Grid: 1024 x 256.
// ---------------------------------------------------------------------------
__global__ __launch_bounds__(256) void gather_kernel(
    const int* __restrict__ see, const int* __restrict__ cnt,
    const float* __restrict__ node_c, const float* __restrict__ rel,
    float* __restrict__ out_node, float* __restrict__ out_edge)
{
    __shared__ int s_s[NN];

    const int t = threadIdx.x;
    const int bi = blockIdx.x;        // b*NN + i
    const int b = bi >> 6;
    const int c = cnt[bi];

    if (t < NN) s_s[t] = see[bi * NN + t];
    __syncthreads();

    // node part: out_node[bi][k][:] = node_c[b, s_k] * (k < c)
    if (t < NN) {
        const float m = (t < c) ? 1.f : 0.f;
        const float4* src = (const float4*)(node_c + (size_t)(b * NN + s_s[t]) * UD);
        float4 v0 = src[0], v1 = src[1];
        v0.x *= m; v0.y *= m; v0.z *= m; v0.w *= m;
        v1.x *= m; v1.y *= m; v1.z *= m; v1.w *= m;
        float4* dst = (float4*)(out_node + ((size_t)bi * NN + t) * UD);
        dst[0] = v0;
        dst[1] = v1;
    }

    const float* relb = rel + (size_t)b * NN * NN * RD;
    float* outb = out_edge + (size_t)bi * NN * NN * RD;

    const int total = c * c;
    for (int task = t; task < total; task += 256) {
        int j = task / c;
        int k = task - j * c;
        const float4* src =
            (const float4*)(relb + (size_t)(s_s[j] * NN + s_s[k]) * RD);
        float4 v0 = src[0], v1 = src[1];
        float4* dst = (float4*)(outb + ((size_t)j * NN + k) * RD);
        dst[0] = v0;
        dst[1] = v1;
    }
}

// ---------------------------------------------------------------------------
extern "C" void kernel_launch(void* const* d_in, const int* in_sizes, int n_in,
                              void* d_out, int out_size, void* d_ws, size_t ws_size,
                              hipStream_t stream)
{
    const float* roi  = (const float*)d_in[0];
    const float* bbox = (const float*)d_in[1];
    const float* dirs = (const float*)d_in[2];
    const float* prio = (const float*)d_in[3];
    const float* w1   = (const float*)d_in[4];
    const float* b1   = (const float*)d_in[5];
    const float* g1   = (const float*)d_in[6];
    const float* bt1  = (const float*)d_in[7];
    const float* m1   = (const float*)d_in[8];
    const float* v1   = (const float*)d_in[9];
    const float* w2   = (const float*)d_in[10];
    const float* b2   = (const float*)d_in[11];
    const float* g2   = (const float*)d_in[12];
    const float* bt2  = (const float*)d_in[13];
    const float* m2   = (const float*)d_in[14];
    const float* v2   = (const float*)d_in[15];
    const float* w3   = (const float*)d_in[16];
    const float* b3   = (const float*)d_in[17];
    const float* wn   = (const float*)d_in[18];
    const float* bnc  = (const float*)d_in[19];
    const float* we1  = (const float*)d_in[20];
    const float* be1  = (const float*)d_in[21];
    const float* we2  = (const float*)d_in[22];
    const float* be2  = (const float*)d_in[23];
    const float* wei  = (const float*)d_in[24];
    const float* bei  = (const float*)d_in[25];
    const int* edge_index = (const int*)d_in[26];

    char* ws = (char*)d_ws;
    int*   see    = (int*)ws;   ws += (size_t)BB * NN * NN * 4;
    int*   cnt    = (int*)ws;   ws += (size_t)BB * NN * 4;
    float* Pbuf   = (float*)ws; ws += (size_t)BB * NN * EH1D * 4;
    float* Qbuf   = (float*)ws; ws += (size_t)BB * NN * EH1D * 4;
    float* node_c = (float*)ws; ws += (size_t)BB * NN * UD * 4;
    float* rel    = (float*)ws; ws += (size_t)BB * NN * NN * RD * 4;

    float* out_node = (float*)d_out;
    float* out_edge = (float*)d_out + (size_t)BB * NN * NN * UD;

    hipLaunchKernelGGL(fused1_kernel, dim3(BB + 256 + BB * NN), dim3(256), 0, stream,
                       edge_index, bbox, dirs, prio, we1, be1,
                       see, cnt, Pbuf, Qbuf,
                       roi, w1, b1, g1, bt1, m1, v1,
                       w2, b2, g2, bt2, m2, v2,
                       w3, b3, wn, bnc, node_c, out_edge);
    hipLaunchKernelGGL(edge_mlp_kernel, dim3(BB * NN), dim3(256), 0, stream,
                       Pbuf, Qbuf, we2, be2, wei, bei, rel);
    hipLaunchKernelGGL(gather_kernel, dim3(BB * NN), dim3(256), 0, stream,
                       see, cnt, node_c, rel, out_node, out_edge);
}

// Round 8
// 249.366 us; speedup vs baseline: 1.0474x; 1.0061x over previous
//
#include <hip/hip_runtime.h>
#include <math.h>

#define BB    16
#define NN    64
#define EE    512
#define CIMG  512
#define H1D   256
#define H2D   128
#define H3D   64
#define UD    8
#define RD    8
#define BBCD  9
#define EH1D  64
#define EH2D  64
#define EPSF  1e-5f

typedef float nfloat4 __attribute__((ext_vector_type(4)));  // native vec for nontemporal builtins

// ---------------------------------------------------------------------------
// Launch A (all compute, no big write):
//   blocks [0,16)      prep: see/cnt via per-dst ordered scan
//   blocks [16,272)    node MLP (K-split across waves, LDS reduction)
//   blocks [272,1296)  edge MLP per (b,i), P/Q computed inline from attr+we1
// LDS union is 43 KB but no write-bound path lives here (R6 lesson), and
// node path runs 1 block/CU regardless; edge path gets 3 blocks/CU — enough
// for VALU-bound GEMM.
// ---------------------------------------------------------------------------
__global__ __launch_bounds__(256) void fusedA_kernel(
    const int* __restrict__ edge_index,
    const float* __restrict__ bboxes,
    const float* __restrict__ dirs,
    const float* __restrict__ prios,
    const float* __restrict__ we1, const float* __restrict__ be1,
    int* __restrict__ see, int* __restrict__ cnt,
    const float* __restrict__ roi,
    const float* __restrict__ w1, const float* __restrict__ b1,
    const float* __restrict__ g1, const float* __restrict__ bt1,
    const float* __restrict__ m1, const float* __restrict__ v1,
    const float* __restrict__ w2, const float* __restrict__ b2,
    const float* __restrict__ g2, const float* __restrict__ bt2,
    const float* __restrict__ m2, const float* __restrict__ v2,
    const float* __restrict__ w3, const float* __restrict__ b3,
    const float* __restrict__ wn, const float* __restrict__ bnc,
    float* __restrict__ node_c,
    const float* __restrict__ we2, const float* __restrict__ be2,
    const float* __restrict__ wei, const float* __restrict__ bei,
    float* __restrict__ rel)
{
    __shared__ union {
        struct {                       // prep path
            int src[EE];
            int dst[EE];
            int see[NN * NN];
        } p;
        struct {                       // node MLP path
            float part[4096];
            float h1[4][H1D];
            float h2[4][H2D];
            float h3[4][H3D];
        } n;
        struct {                       // edge MLP path
            float e1[NN * 68];         // e1 then e2 (row stride 68)
            float qw[NN * EH1D];       // we2
            float wei[EH2D * RD];
            float attr[NN][BBCD];
            float we1[2 * BBCD * EH1D];
            float Pi[EH1D];            // P[i] + be1 folded in
            float be2[EH2D];
            float bei[RD];
        } e;
    } sm;

    const int t = threadIdx.x;

    // ======================== prep path ====================================
    if (blockIdx.x < BB) {
        const int b = blockIdx.x;
        const int* ei = edge_index + b * 2 * EE;
        for (int e = t; e < EE; e += 256) {
            sm.p.src[e] = ei[e];
            sm.p.dst[e] = ei[EE + e];
        }
        for (int x = t; x < NN * NN; x += 256)
            sm.p.see[x] = ((x & (NN - 1)) == 0) ? (x >> 6) : 0;
        __syncthreads();

        if (t < NN) {
            int pos = 0;
            #pragma unroll 8
            for (int e = 0; e < EE; ++e) {
                if (sm.p.dst[e] == t) {
                    ++pos;
                    if (pos < NN) sm.p.see[t * NN + pos] = sm.p.src[e];
                }
            }
            int c = pos + 1;
            cnt[b * NN + t] = (c < NN) ? c : NN;
        }
        __syncthreads();

        int4* dst4 = (int4*)(see + b * NN * NN);
        const int4* src4 = (const int4*)sm.p.see;
        for (int x = t; x < (NN * NN) / 4; x += 256) dst4[x] = src4[x];
        return;
    }

    // ======================== edge MLP path ================================
    if (blockIdx.x >= BB + 256) {
        const int id = blockIdx.x - (BB + 256);
        const int b = id >> 6;
        const int i = id & 63;

        if (t < NN) {
            const float* bbp = bboxes + (b * NN + t) * 4;
            const float* ddp = dirs + (b * NN + t) * 4;
            sm.e.attr[t][0] = bbp[0] * (1.0f / 1024.0f);
            sm.e.attr[t][1] = bbp[1] * (1.0f / 1024.0f);
            sm.e.attr[t][2] = bbp[2] * (1.0f / 1024.0f);
            sm.e.attr[t][3] = bbp[3] * (1.0f / 1024.0f);
            sm.e.attr[t][4] = ddp[0];
            sm.e.attr[t][5] = ddp[1];
            sm.e.attr[t][6] = ddp[2];
            sm.e.attr[t][7] = ddp[3];
            sm.e.attr[t][8] = prios[b * NN + t];
        }
        for (int x = t; x < 2 * BBCD * EH1D; x += 256) sm.e.we1[x] = we1[x];
        {
            const float4* w4 = (const float4*)we2;
            float4* qw4 = (float4*)sm.e.qw;
            #pragma unroll
            for (int x = 0; x < 4; ++x) qw4[x * 256 + t] = w4[x * 256 + t];
        }
        if (t < 128) ((float4*)sm.e.wei)[t] = ((const float4*)wei)[t];
        if (t < EH2D) sm.e.be2[t] = be2[t];
        if (t < RD) sm.e.bei[t] = bei[t];
        __syncthreads();

        // Pi[o] = attr[i] @ we1[:9, o] + be1[o]
        if (t < EH1D) {
            float p = be1[t];
            #pragma unroll
            for (int c = 0; c < BBCD; ++c)
                p = fmaf(sm.e.attr[i][c], sm.e.we1[c * EH1D + t], p);
            sm.e.Pi[t] = p;
        }
        __syncthreads();

        // e1[j][o] = relu(Pi[o] + attr[j] @ we1[9:, o])
        {
            const int o = t & 63;
            const int jw = t >> 6;       // wave index, uniform
            #pragma unroll
            for (int jg = 0; jg < 16; ++jg) {
                const int j = jg * 4 + jw;
                float a = sm.e.Pi[o];
                #pragma unroll
                for (int c = 0; c < BBCD; ++c)
                    a = fmaf(sm.e.attr[j][c], sm.e.we1[(BBCD + c) * EH1D + o], a);
                sm.e.e1[j * 68 + o] = fmaxf(0.f, a);
            }
        }
        __syncthreads();

        // e2[j][o2] = relu(e1 @ we2 + be2) via 4x4 register blocking
        const int tx = t & 15, ty = t >> 4;
        const int o0 = tx * 4, j0 = ty * 4;
        float acc[4][4];
        #pragma unroll
        for (int r = 0; r < 4; ++r)
            #pragma unroll
            for (int o = 0; o < 4; ++o) acc[r][o] = 0.f;

        #pragma unroll 4
        for (int cg = 0; cg < 16; ++cg) {
            float ev[4][4];
            #pragma unroll
            for (int r = 0; r < 4; ++r) {
                float4 v = *(const float4*)(sm.e.e1 + (j0 + r) * 68 + cg * 4);
                ev[r][0] = v.x; ev[r][1] = v.y; ev[r][2] = v.z; ev[r][3] = v.w;
            }
            #pragma unroll
            for (int q = 0; q < 4; ++q) {
                float4 wv = *(const float4*)(sm.e.qw + (cg * 4 + q) * EH1D + o0);
                #pragma unroll
                for (int r = 0; r < 4; ++r) {
                    acc[r][0] = fmaf(ev[r][q], wv.x, acc[r][0]);
                    acc[r][1] = fmaf(ev[r][q], wv.y, acc[r][1]);
                    acc[r][2] = fmaf(ev[r][q], wv.z, acc[r][2]);
                    acc[r][3] = fmaf(ev[r][q], wv.w, acc[r][3]);
                }
            }
        }

        {
            float4 bv = *(const float4*)(sm.e.be2 + o0);
            #pragma unroll
            for (int r = 0; r < 4; ++r) {
                float4 v;
                v.x = fmaxf(0.f, acc[r][0] + bv.x);
                v.y = fmaxf(0.f, acc[r][1] + bv.y);
                v.z = fmaxf(0.f, acc[r][2] + bv.z);
                v.w = fmaxf(0.f, acc[r][3] + bv.w);
                *(float4*)(sm.e.e1 + (j0 + r) * 68 + o0) = v;
            }
        }
        __syncthreads();

        // layer 3 + sigmoid
        {
            const int j = t >> 2;
            const int r0 = (t & 3) * 2;
            float a0 = sm.e.bei[r0], a1 = sm.e.bei[r0 + 1];
            const float* e2row = sm.e.e1 + j * 68;
            #pragma unroll
            for (int og = 0; og < 16; ++og) {
                float4 e2v = *(const float4*)(e2row + og * 4);
                float2 w0 = *(const float2*)(sm.e.wei + (og * 4 + 0) * RD + r0);
                float2 w1 = *(const float2*)(sm.e.wei + (og * 4 + 1) * RD + r0);
                float2 w2 = *(const float2*)(sm.e.wei + (og * 4 + 2) * RD + r0);
                float2 w3 = *(const float2*)(sm.e.wei + (og * 4 + 3) * RD + r0);
                a0 = fmaf(e2v.x, w0.x, a0); a1 = fmaf(e2v.x, w0.y, a1);
                a0 = fmaf(e2v.y, w1.x, a0); a1 = fmaf(e2v.y, w1.y, a1);
                a0 = fmaf(e2v.z, w2.x, a0); a1 = fmaf(e2v.z, w2.y, a1);
                a0 = fmaf(e2v.w, w3.x, a0); a1 = fmaf(e2v.w, w3.y, a1);
            }
            float2 o;
            o.x = 1.f / (1.f + expf(-a0));
            o.y = 1.f / (1.f + expf(-a1));
            *(float2*)(rel + ((size_t)id * NN + j) * RD + r0) = o;
        }
        return;
    }

    // ======================== node MLP path ================================
    const int row0 = (blockIdx.x - BB) * 4;
    float* part = sm.n.part;

    // layer 1: 512 -> 256. og = t&63 (4 cols), kg = t>>6 (K/4 slice)
    {
        const int og = t & 63, kg = t >> 6;
        const float4* w1v = (const float4*)w1;
        const float4* roiv = (const float4*)(roi + (size_t)row0 * CIMG);
        float acc[4][4];
        #pragma unroll
        for (int r = 0; r < 4; ++r)
            #pragma unroll
            for (int c = 0; c < 4; ++c) acc[r][c] = 0.f;

        for (int cq = 0; cq < 32; ++cq) {
            const int c4 = kg * 32 + cq;
            float x[4][4], w[4][4];
            #pragma unroll
            for (int r = 0; r < 4; ++r) {
                float4 v = roiv[r * 128 + c4];
                x[r][0] = v.x; x[r][1] = v.y; x[r][2] = v.z; x[r][3] = v.w;
            }
            #pragma unroll
            for (int q = 0; q < 4; ++q) {
                float4 v = w1v[(size_t)(c4 * 4 + q) * 64 + og];
                w[q][0] = v.x; w[q][1] = v.y; w[q][2] = v.z; w[q][3] = v.w;
            }
            #pragma unroll
            for (int r = 0; r < 4; ++r)
                #pragma unroll
                for (int q = 0; q < 4; ++q)
                    #pragma unroll
                    for (int c = 0; c < 4; ++c)
                        acc[r][c] = fmaf(x[r][q], w[q][c], acc[r][c]);
        }
        #pragma unroll
        for (int r = 0; r < 4; ++r) {
            float4 v = {acc[r][0], acc[r][1], acc[r][2], acc[r][3]};
            *(float4*)(part + (kg * 4 + r) * 256 + og * 4) = v;
        }
    }
    __syncthreads();
    {
        const int o = t;
        const float bias = b1[o];
        const float scale = rsqrtf(v1[o] + EPSF) * g1[o];
        const float beta = bt1[o];
        const float mu = m1[o];
        #pragma unroll
        for (int r = 0; r < 4; ++r) {
            float s = part[(0 * 4 + r) * 256 + o] + part[(1 * 4 + r) * 256 + o]
                    + part[(2 * 4 + r) * 256 + o] + part[(3 * 4 + r) * 256 + o];
            sm.n.h1[r][o] = fmaxf(0.f, (s + bias - mu) * scale + beta);
        }
    }
    __syncthreads();

    // layer 2: 256 -> 128
    {
        const int og = t & 31, kg = t >> 5;
        const float4* w2v = (const float4*)w2;
        float acc[4][4];
        #pragma unroll
        for (int r = 0; r < 4; ++r)
            #pragma unroll
            for (int c = 0; c < 4; ++c) acc[r][c] = 0.f;

        #pragma unroll
        for (int cq = 0; cq < 8; ++cq) {
            const int c4 = kg * 8 + cq;
            float x[4][4], w[4][4];
            #pragma unroll
            for (int r = 0; r < 4; ++r) {
                float4 v = *(const float4*)&sm.n.h1[r][c4 * 4];
                x[r][0] = v.x; x[r][1] = v.y; x[r][2] = v.z; x[r][3] = v.w;
            }
            #pragma unroll
            for (int q = 0; q < 4; ++q) {
                float4 v = w2v[(size_t)(c4 * 4 + q) * 32 + og];
                w[q][0] = v.x; w[q][1] = v.y; w[q][2] = v.z; w[q][3] = v.w;
            }
            #pragma unroll
            for (int r = 0; r < 4; ++r)
                #pragma unroll
                for (int q = 0; q < 4; ++q)
                    #pragma unroll
                    for (int c = 0; c < 4; ++c)
                        acc[r][c] = fmaf(x[r][q], w[q][c], acc[r][c]);
        }
        #pragma unroll
        for (int r = 0; r < 4; ++r) {
            float4 v = {acc[r][0], acc[r][1], acc[r][2], acc[r][3]};
            *(float4*)(part + (kg * 4 + r) * 128 + og * 4) = v;
        }
    }
    __syncthreads();
    {
        const int o = t & 127;
        const int rp = t >> 7;
        const float bias = b2[o];
        const float scale = rsqrtf(v2[o] + EPSF) * g2[o];
        const float beta = bt2[o];
        const float mu = m2[o];
        #pragma unroll
        for (int rr = 0; rr < 2; ++rr) {
            const int r = rp + rr * 2;
            float s = 0.f;
            #pragma unroll
            for (int kg = 0; kg < 8; ++kg) s += part[(kg * 4 + r) * 128 + o];
            sm.n.h2[r][o] = fmaxf(0.f, (s + bias - mu) * scale + beta);
        }
    }
    __syncthreads();

    // layer 3: 128 -> 64
    {
        const int og = t & 15, kg = t >> 4;
        const float4* w3v = (const float4*)w3;
        float acc[4][4];
        #pragma unroll
        for (int r = 0; r < 4; ++r)
            #pragma unroll
            for (int c = 0; c < 4; ++c) acc[r][c] = 0.f;

        #pragma unroll
        for (int cq = 0; cq < 2; ++cq) {
            const int c4 = kg * 2 + cq;
            float x[4][4], w[4][4];
            #pragma unroll
            for (int r = 0; r < 4; ++r) {
                float4 v = *(const float4*)&sm.n.h2[r][c4 * 4];
                x[r][0] = v.x; x[r][1] = v.y; x[r][2] = v.z; x[r][3] = v.w;
            }
            #pragma unroll
            for (int q = 0; q < 4; ++q) {
                float4 v = w3v[(size_t)(c4 * 4 + q) * 16 + og];
                w[q][0] = v.x; w[q][1] = v.y; w[q][2] = v.z; w[q][3] = v.w;
            }
            #pragma unroll
            for (int r = 0; r < 4; ++r)
                #pragma unroll
                for (int q = 0; q < 4; ++q)
                    #pragma unroll
                    for (int c = 0; c < 4; ++c)
                        acc[r][c] = fmaf(x[r][q], w[q][c], acc[r][c]);
        }
        #pragma unroll
        for (int r = 0; r < 4; ++r) {
            float4 v = {acc[r][0], acc[r][1], acc[r][2], acc[r][3]};
            *(float4*)(part + (kg * 4 + r) * 64 + og * 4) = v;
        }
    }
    __syncthreads();
    {
        const int o = t & 63;
        const int r = t >> 6;
        float s = b3[o];
        #pragma unroll
        for (int kg = 0; kg < 16; ++kg) s += part[(kg * 4 + r) * 64 + o];
        sm.n.h3[r][o] = fmaxf(0.f, s);
    }
    __syncthreads();

    if (t < 32) {
        const int o = t & 7, r = t >> 3;
        float a = bnc[o];
        #pragma unroll 8
        for (int c = 0; c < H3D; ++c) a = fmaf(sm.n.h3[r][c], wn[c * UD + o], a);
        node_c[(size_t)(row0 + r) * UD + o] = 1.f / (1.f + expf(-a));
    }
}

// ---------------------------------------------------------------------------
// Launch B: single-pass slab writer. Per block (b,i): write the full
// 64x64x8 slab once — gathered rel values where j,k < cnt (rel is 2 MB,
// L2-resident), NT zeros elsewhere — plus the node_concepts row.
// j is wave-uniform (branch via execz). Write-bound ~= 134 MB.
// ---------------------------------------------------------------------------
__global__ __launch_bounds__(256) void gatherfill_kernel(
    const int* __restrict__ see, const int* __restrict__ cnt,
    const float* __restrict__ node_c, const float* __restrict__ rel,
    float* __restrict__ out_node, float* __restrict__ out_edge)
{
    __shared__ int s_s[NN];

    const int t = threadIdx.x;
    const int bi = blockIdx.x;        // b*NN + i
    const int b = bi >> 6;
    const int c = cnt[bi];

    if (t < NN) s_s[t] = see[bi * NN + t];
    __syncthreads();

    // node row: out_node[bi][k][:] = node_c[b, s_k] * (k < c)
    if (t < NN) {
        const float m = (t < c) ? 1.f : 0.f;
        const float4* src = (const float4*)(node_c + (size_t)(b * NN + s_s[t]) * UD);
        float4 v0 = src[0], v1 = src[1];
        v0.x *= m; v0.y *= m; v0.z *= m; v0.w *= m;
        v1.x *= m; v1.y *= m; v1.z *= m; v1.w *= m;
        float4* dst = (float4*)(out_node + ((size_t)bi * NN + t) * UD);
        dst[0] = v0;
        dst[1] = v1;
    }

    const float* relb = rel + (size_t)b * NN * NN * RD;
    float* outb = out_edge + (size_t)bi * NN * NN * RD;
    const nfloat4 z = {0.f, 0.f, 0.f, 0.f};

    #pragma unroll
    for (int it = 0; it < (NN * NN) / 256; ++it) {
        const int task = it * 256 + t;
        const int j = task >> 6;       // wave-uniform
        const int k = task & 63;
        nfloat4* dst = (nfloat4*)(outb + (size_t)task * RD);
        if (j < c) {
            if (k < c) {
                const float4* src =
                    (const float4*)(relb + (size_t)(s_s[j] * NN + s_s[k]) * RD);
                float4 v0 = src[0], v1 = src[1];
                ((float4*)dst)[0] = v0;
                ((float4*)dst)[1] = v1;
            } else {
                __builtin_nontemporal_store(z, dst);
                __builtin_nontemporal_store(z, dst + 1);
            }
        } else {
            __builtin_nontemporal_store(z, dst);
            __builtin_nontemporal_store(z, dst + 1);
        }
    }
}

// ---------------------------------------------------------------------------
extern "C" void kernel_launch(void* const* d_in, const int* in_sizes, int n_in,
                              void* d_out, int out_size, void* d_ws, size_t ws_size,
                              hipStream_t stream)
{
    const float* roi  = (const float*)d_in[0];
    const float* bbox = (const float*)d_in[1];
    const float* dirs = (const float*)d_in[2];
    const float* prio = (const float*)d_in[3];
    const float* w1   = (const float*)d_in[4];
    const float* b1   = (const float*)d_in[5];
    const float* g1   = (const float*)d_in[6];
    const float* bt1  = (const float*)d_in[7];
    const float* m1   = (const float*)d_in[8];
    const float* v1   = (const float*)d_in[9];
    const float* w2   = (const float*)d_in[10];
    const float* b2   = (const float*)d_in[11];
    const float* g2   = (const float*)d_in[12];
    const float* bt2  = (const float*)d_in[13];
    const float* m2   = (const float*)d_in[14];
    const float* v2   = (const float*)d_in[15];
    const float* w3   = (const float*)d_in[16];
    const float* b3   = (const float*)d_in[17];
    const float* wn   = (const float*)d_in[18];
    const float* bnc  = (const float*)d_in[19];
    const float* we1  = (const float*)d_in[20];
    const float* be1  = (const float*)d_in[21];
    const float* we2  = (const float*)d_in[22];
    const float* be2  = (const float*)d_in[23];
    const float* wei  = (const float*)d_in[24];
    const float* bei  = (const float*)d_in[25];
    const int* edge_index = (const int*)d_in[26];

    char* ws = (char*)d_ws;
    int*   see    = (int*)ws;   ws += (size_t)BB * NN * NN * 4;
    int*   cnt    = (int*)ws;   ws += (size_t)BB * NN * 4;
    float* node_c = (float*)ws; ws += (size_t)BB * NN * UD * 4;
    float* rel    = (float*)ws; ws += (size_t)BB * NN * NN * RD * 4;

    float* out_node = (float*)d_out;
    float* out_edge = (float*)d_out + (size_t)BB * NN * NN * UD;

    hipLaunchKernelGGL(fusedA_kernel,
                       dim3(BB + 256 + BB * NN), dim3(256), 0, stream,
                       edge_index, bbox, dirs, prio, we1, be1,
                       see, cnt,
                       roi, w1, b1, g1, bt1, m1, v1,
                       w2, b2, g2, bt2, m2, v2,
                       w3, b3, wn, bnc, node_c,
                       we2, be2, wei, bei, rel);
    hipLaunchKernelGGL(gatherfill_kernel, dim3(BB * NN), dim3(256), 0, stream,
                       see, cnt, node_c, rel, out_node, out_edge);
}